// Round 1
// baseline (280.177 us; speedup 1.0000x reference)
//
#include <hip/hip_runtime.h>
#include <math.h>

// Problem constants (B=16, C=3 -> 48 planes of 512x512)
#define H_IMG 512
#define W_IMG 512
#define TH 32
#define TW 32
#define HALO 5
#define WS11 11
#define SH (TH + 2*HALO)   // 42 halo rows
#define SWD (TW + 2*HALO)  // 42 halo cols
#define SWP 44             // padded LDS row stride
#define NTHREADS 256

// 1D Gaussian window, normalized so outer(w,w) == reference's 2D window.
__device__ __forceinline__ void make_win(float* w) {
    float g[WS11];
    float s = 0.f;
#pragma unroll
    for (int i = 0; i < WS11; ++i) {
        float c = (float)(i - WS11/2);
        g[i] = expf(-c*c / (2.f*1.5f*1.5f));
        s += g[i];
    }
    float inv = 1.f / s;
#pragma unroll
    for (int i = 0; i < WS11; ++i) w[i] = g[i]*inv;
}

// Fused SSIM + MSE over one 32x32 tile. Separable 11-tap conv of the 5
// fields {x, y, x^2, y^2, xy} with zero padding (matches lax.conv pad=5).
__global__ __launch_bounds__(NTHREADS) void ssim_mse_tile(
        const float* __restrict__ cover, const float* __restrict__ wmed,
        float* __restrict__ part, int nParts) {
    __shared__ float sx[SH*SWP];        // 7392 B
    __shared__ float sy[SH*SWP];        // 7392 B
    __shared__ float rbuf[5*SH*TW];     // 26880 B: row-conv of 5 fields
    __shared__ float red[8];

    const int tid = threadIdx.x;
    const size_t pbase = (size_t)blockIdx.z * (H_IMG*W_IMG);
    const float* xp = wmed + pbase;     // x = wmed, y = cover (as in reference)
    const float* yp = cover + pbase;
    const int ty0 = blockIdx.y*TH - HALO;
    const int tx0 = blockIdx.x*TW - HALO;

    float w[WS11];
    make_win(w);

    // Stage 1: halo tile (zero outside the plane == zero padding)
    for (int idx = tid; idx < SH*SWD; idx += NTHREADS) {
        int r = idx / SWD, c = idx - r*SWD;
        int gy = ty0 + r, gx = tx0 + c;
        float xv = 0.f, yv = 0.f;
        if ((unsigned)gy < (unsigned)H_IMG && (unsigned)gx < (unsigned)W_IMG) {
            size_t o = (size_t)gy*W_IMG + gx;
            xv = xp[o]; yv = yp[o];
        }
        sx[r*SWP + c] = xv;
        sy[r*SWP + c] = yv;
    }
    __syncthreads();

    // Stage 2: horizontal 11-tap conv of 5 fields, for all 42 halo rows
    for (int idx = tid; idx < SH*TW; idx += NTHREADS) {
        int r = idx >> 5, c = idx & 31;
        float ax = 0.f, ay = 0.f, axx = 0.f, ayy = 0.f, axy = 0.f;
        const float* px = &sx[r*SWP + c];
        const float* py = &sy[r*SWP + c];
#pragma unroll
        for (int j = 0; j < WS11; ++j) {
            float wv = w[j];
            float xv = px[j], yv = py[j];
            ax  += wv*xv;
            ay  += wv*yv;
            axx += wv*xv*xv;
            ayy += wv*yv*yv;
            axy += wv*xv*yv;
        }
        rbuf[(0*SH + r)*TW + c] = ax;
        rbuf[(1*SH + r)*TW + c] = ay;
        rbuf[(2*SH + r)*TW + c] = axx;
        rbuf[(3*SH + r)*TW + c] = ayy;
        rbuf[(4*SH + r)*TW + c] = axy;
    }
    __syncthreads();

    // Stage 3: vertical 11-tap conv + SSIM formula + fused MSE
    const float C1 = 0.01f*0.01f, C2 = 0.03f*0.03f;
    float ssim_acc = 0.f, mse_acc = 0.f;
    for (int idx = tid; idx < TH*TW; idx += NTHREADS) {  // exactly 4 iters
        int r = idx >> 5, c = idx & 31;
        float mx = 0.f, my = 0.f, exx = 0.f, eyy = 0.f, exy = 0.f;
#pragma unroll
        for (int i = 0; i < WS11; ++i) {
            float wv = w[i];
            mx  += wv * rbuf[(0*SH + r+i)*TW + c];
            my  += wv * rbuf[(1*SH + r+i)*TW + c];
            exx += wv * rbuf[(2*SH + r+i)*TW + c];
            eyy += wv * rbuf[(3*SH + r+i)*TW + c];
            exy += wv * rbuf[(4*SH + r+i)*TW + c];
        }
        float sxx = exx - mx*mx;
        float syy = eyy - my*my;
        float sxy = exy - mx*my;
        float num = (2.f*mx*my + C1) * (2.f*sxy + C2);
        float den = (mx*mx + my*my + C1) * (sxx + syy + C2);
        ssim_acc += __fdividef(num, den);
        float xv = sx[(r+HALO)*SWP + (c+HALO)];
        float yv = sy[(r+HALO)*SWP + (c+HALO)];
        float d = xv - yv;
        mse_acc += d*d;
    }

    // Block reduce (4 waves of 64)
#pragma unroll
    for (int off = 32; off > 0; off >>= 1) {
        ssim_acc += __shfl_down(ssim_acc, off);
        mse_acc  += __shfl_down(mse_acc, off);
    }
    int wid = tid >> 6, lane = tid & 63;
    if (lane == 0) { red[wid] = ssim_acc; red[4+wid] = mse_acc; }
    __syncthreads();
    if (tid == 0) {
        float s = red[0]+red[1]+red[2]+red[3];
        float m = red[4]+red[5]+red[6]+red[7];
        int bid = (blockIdx.z*gridDim.y + blockIdx.y)*gridDim.x + blockIdx.x;
        part[bid] = s;
        part[nParts + bid] = m;
    }
}

// Single-block: reduce tile partials (double), BCE loss, curriculum weights.
__global__ __launch_bounds__(NTHREADS) void finalize_k(
        const float* __restrict__ part, int nParts,
        const float* __restrict__ wm_orig, const float* __restrict__ wm_ext,
        int nWm, const int* __restrict__ epoch_p,
        float* __restrict__ out, double inv_npix, double inv_nwm) {
    __shared__ double red[12];
    int tid = threadIdx.x;
    double s_ssim = 0.0, s_mse = 0.0, s_wl = 0.0;
    for (int i = tid; i < nParts; i += NTHREADS) {
        s_ssim += (double)part[i];
        s_mse  += (double)part[nParts + i];
    }
    for (int i = tid; i < nWm; i += NTHREADS) {
        float p = wm_orig[i], q = wm_ext[i];
        s_wl += (double)(-(p*logf(q) + (1.f-p)*logf(1.f-q)));
    }
#pragma unroll
    for (int off = 32; off > 0; off >>= 1) {
        s_ssim += __shfl_down(s_ssim, off);
        s_mse  += __shfl_down(s_mse, off);
        s_wl   += __shfl_down(s_wl, off);
    }
    int wid = tid >> 6, lane = tid & 63;
    if (lane == 0) { red[wid] = s_ssim; red[4+wid] = s_mse; red[8+wid] = s_wl; }
    __syncthreads();
    if (tid == 0) {
        double ssim_sum = red[0]+red[1]+red[2]+red[3];
        double mse_sum  = red[4]+red[5]+red[6]+red[7];
        double wl_sum   = red[8]+red[9]+red[10]+red[11];
        float sv = (float)(ssim_sum * inv_npix);
        float ml = (float)(mse_sum  * inv_npix);
        float wl = (float)(wl_sum   * inv_nwm);
        int e = *epoch_p;
        float w_img, w_ssim;
        if (e <= 12) {
            w_img = 0.05f; w_ssim = 0.05f;
        } else {
            float progress = fminf(1.0f, (float)(e - 12) / 10.0f);
            w_img  = 0.05f + (0.5f - 0.05f)*progress;
            w_ssim = 0.05f + (0.8f - 0.05f)*progress;
        }
        float sl = 1.0f - sv;
        float total = w_img*ml + w_ssim*sl + 3.0f*wl;
        out[0] = total;
        out[1] = ml;
        out[2] = sv;
        out[3] = wl;
    }
}

extern "C" void kernel_launch(void* const* d_in, const int* in_sizes, int n_in,
                              void* d_out, int out_size, void* d_ws, size_t ws_size,
                              hipStream_t stream) {
    const float* cover   = (const float*)d_in[0];
    const float* wmed    = (const float*)d_in[1];
    const float* wm_orig = (const float*)d_in[2];
    const float* wm_ext  = (const float*)d_in[3];
    const int*   epoch   = (const int*)d_in[4];
    float* out = (float*)d_out;

    int npix   = in_sizes[0];                 // 12,582,912
    int planes = npix / (H_IMG * W_IMG);      // 48
    int nWm    = in_sizes[2];                 // 16,384

    dim3 grid(W_IMG/TW, H_IMG/TH, planes);    // 16 x 16 x 48 = 12288 blocks
    int nParts = grid.x * grid.y * grid.z;
    float* part = (float*)d_ws;               // 2 * nParts floats (98 KB)

    ssim_mse_tile<<<grid, NTHREADS, 0, stream>>>(cover, wmed, part, nParts);
    finalize_k<<<1, NTHREADS, 0, stream>>>(part, nParts, wm_orig, wm_ext, nWm,
                                           epoch, out,
                                           1.0 / (double)npix, 1.0 / (double)nWm);
}

// Round 2
// 232.128 us; speedup vs baseline: 1.2070x; 1.2070x over previous
//
#include <hip/hip_runtime.h>
#include <math.h>

// Problem constants (B=16, C=3 -> 48 planes of 512x512)
#define H_IMG 512
#define W_IMG 512
#define TH 32
#define TW 32
#define HALO 5
#define WS11 11
#define SH (TH + 2*HALO)   // 42 halo rows
#define SWD (TW + 2*HALO)  // 42 halo cols
#define SWP 48             // padded LDS row stride (mult of 4 -> b128-aligned)
#define RW  TW             // rbuf row stride (32: col c -> bank c, 2-way free)
#define NTHREADS 256

// Gaussian 11-tap window, sigma=1.5, normalized (outer(w,w) == ref 2D window).
// Compile-time constants -> land in SGPRs, no per-thread expf.
#define W0 0.00102838f
#define W1 0.00759873f
#define W2 0.03600075f
#define W3 0.10936070f
#define W4 0.21300556f
#define W5 0.26601172f
__device__ __constant__ float c_w[WS11] = {W0,W1,W2,W3,W4,W5,W4,W3,W2,W1,W0};

// Fused SSIM + MSE over one 32x32 tile; separable 11-tap conv of 5 fields.
__global__ __launch_bounds__(NTHREADS) void ssim_mse_tile(
        const float* __restrict__ cover, const float* __restrict__ wmed,
        float* __restrict__ part, int nParts) {
    __shared__ __align__(16) float sx[SH*SWP];     // 8064 B
    __shared__ __align__(16) float sy[SH*SWP];     // 8064 B
    __shared__ __align__(16) float rbuf[5*SH*RW];  // 26880 B
    __shared__ float red[8];

    const int tid = threadIdx.x;
    const size_t pbase = (size_t)blockIdx.z * (H_IMG*W_IMG);
    const float* xp = wmed + pbase;     // x = wmed, y = cover (as in reference)
    const float* yp = cover + pbase;
    const int ty0 = blockIdx.y*TH - HALO;
    const int tx0 = blockIdx.x*TW - HALO;

    // ---- Stage 1: halo load (zero pad outside plane) + fused MSE ----
    float mse_acc = 0.f;
    for (int i = tid; i < SH*SWD; i += NTHREADS) {
        int r = i / SWD, c = i - r*SWD;
        int gy = ty0 + r, gx = tx0 + c;
        float xv = 0.f, yv = 0.f;
        if ((unsigned)gy < (unsigned)H_IMG && (unsigned)gx < (unsigned)W_IMG) {
            size_t o = (size_t)gy*W_IMG + gx;
            xv = xp[o]; yv = yp[o];
        }
        sx[r*SWP + c] = xv;
        sy[r*SWP + c] = yv;
        // interior pixel of this tile -> contributes to MSE exactly once
        if (r >= HALO && r < HALO+TH && c >= HALO && c < HALO+TW) {
            float d = xv - yv;
            mse_acc += d*d;
        }
    }
    __syncthreads();

    // ---- Stage 2: horizontal conv, 4 consecutive cols per task ----
    // 42 rows x 8 col-groups = 336 tasks
    for (int t = tid; t < SH*8; t += NTHREADS) {
        int r = t >> 3, c0 = (t & 7) << 2;
        const float4* px4 = (const float4*)&sx[r*SWP + c0];
        const float4* py4 = (const float4*)&sy[r*SWP + c0];
        float4 xa = px4[0], xb = px4[1], xc = px4[2], xd = px4[3];
        float4 ya = py4[0], yb = py4[1], yc = py4[2], yd = py4[3];
        float xv[14] = {xa.x,xa.y,xa.z,xa.w, xb.x,xb.y,xb.z,xb.w,
                        xc.x,xc.y,xc.z,xc.w, xd.x,xd.y};
        float yv[14] = {ya.x,ya.y,ya.z,ya.w, yb.x,yb.y,yb.z,yb.w,
                        yc.x,yc.y,yc.z,yc.w, yd.x,yd.y};
        float ax[4]={0,0,0,0}, ay[4]={0,0,0,0};
        float axx[4]={0,0,0,0}, ayy[4]={0,0,0,0}, axy[4]={0,0,0,0};
#pragma unroll
        for (int j = 0; j < 14; ++j) {
            float px = xv[j], py = yv[j];
            float pxx = px*px, pyy = py*py, pxy = px*py;
#pragma unroll
            for (int k = 0; k < 4; ++k) {
                int tap = j - k;                 // compile-time resolved
                if (tap >= 0 && tap < WS11) {
                    float wv = c_w[tap];
                    ax[k]  = fmaf(wv, px,  ax[k]);
                    ay[k]  = fmaf(wv, py,  ay[k]);
                    axx[k] = fmaf(wv, pxx, axx[k]);
                    ayy[k] = fmaf(wv, pyy, ayy[k]);
                    axy[k] = fmaf(wv, pxy, axy[k]);
                }
            }
        }
        *(float4*)&rbuf[(0*SH + r)*RW + c0] = make_float4(ax[0],ax[1],ax[2],ax[3]);
        *(float4*)&rbuf[(1*SH + r)*RW + c0] = make_float4(ay[0],ay[1],ay[2],ay[3]);
        *(float4*)&rbuf[(2*SH + r)*RW + c0] = make_float4(axx[0],axx[1],axx[2],axx[3]);
        *(float4*)&rbuf[(3*SH + r)*RW + c0] = make_float4(ayy[0],ayy[1],ayy[2],ayy[3]);
        *(float4*)&rbuf[(4*SH + r)*RW + c0] = make_float4(axy[0],axy[1],axy[2],axy[3]);
    }
    __syncthreads();

    // ---- Stage 3: vertical conv, 4 outputs per thread in a COLUMN ----
    // thread -> col c, row group r0..r0+3; taps span 14 rows, read once.
    const float C1 = 0.01f*0.01f, C2 = 0.03f*0.03f;
    const int c  = tid & 31;
    const int r0 = (tid >> 5) << 2;
    float mx[4]={0,0,0,0}, my[4]={0,0,0,0};
    float exx[4]={0,0,0,0}, eyy[4]={0,0,0,0}, exy[4]={0,0,0,0};
#pragma unroll
    for (int f = 0; f < 5; ++f) {
        float v[14];
#pragma unroll
        for (int i = 0; i < 14; ++i)
            v[i] = rbuf[(f*SH + r0 + i)*RW + c];
        float acc[4] = {0,0,0,0};
#pragma unroll
        for (int k = 0; k < 4; ++k)
#pragma unroll
            for (int i = 0; i < WS11; ++i)
                acc[k] = fmaf(c_w[i], v[k+i], acc[k]);
        if (f == 0) { mx[0]=acc[0];mx[1]=acc[1];mx[2]=acc[2];mx[3]=acc[3]; }
        else if (f == 1) { my[0]=acc[0];my[1]=acc[1];my[2]=acc[2];my[3]=acc[3]; }
        else if (f == 2) { exx[0]=acc[0];exx[1]=acc[1];exx[2]=acc[2];exx[3]=acc[3]; }
        else if (f == 3) { eyy[0]=acc[0];eyy[1]=acc[1];eyy[2]=acc[2];eyy[3]=acc[3]; }
        else { exy[0]=acc[0];exy[1]=acc[1];exy[2]=acc[2];exy[3]=acc[3]; }
    }
    float ssim_acc = 0.f;
#pragma unroll
    for (int k = 0; k < 4; ++k) {
        float sxx = exx[k] - mx[k]*mx[k];
        float syy = eyy[k] - my[k]*my[k];
        float sxy = exy[k] - mx[k]*my[k];
        float num = (2.f*mx[k]*my[k] + C1) * (2.f*sxy + C2);
        float den = (mx[k]*mx[k] + my[k]*my[k] + C1) * (sxx + syy + C2);
        ssim_acc += __fdividef(num, den);
    }

    // ---- Block reduce (4 waves of 64) ----
#pragma unroll
    for (int off = 32; off > 0; off >>= 1) {
        ssim_acc += __shfl_down(ssim_acc, off);
        mse_acc  += __shfl_down(mse_acc, off);
    }
    int wid = tid >> 6, lane = tid & 63;
    if (lane == 0) { red[wid] = ssim_acc; red[4+wid] = mse_acc; }
    __syncthreads();
    if (tid == 0) {
        float s = red[0]+red[1]+red[2]+red[3];
        float m = red[4]+red[5]+red[6]+red[7];
        int bid = (blockIdx.z*gridDim.y + blockIdx.y)*gridDim.x + blockIdx.x;
        part[bid] = s;
        part[nParts + bid] = m;
    }
}

// 1024-thread finalize: vectorized partial reduce (double), fast-log BCE,
// curriculum weights.
#define FT 1024
__global__ __launch_bounds__(FT) void finalize_k(
        const float* __restrict__ part, int nParts,
        const float* __restrict__ wm_orig, const float* __restrict__ wm_ext,
        int nWm, const int* __restrict__ epoch_p,
        float* __restrict__ out, double inv_npix, double inv_nwm) {
    __shared__ double red[48];
    int tid = threadIdx.x;
    double s_ssim = 0.0, s_mse = 0.0, s_wl = 0.0;
    const float4* s4 = (const float4*)part;
    const float4* m4 = (const float4*)(part + nParts);
    int n4 = nParts >> 2;
    for (int i = tid; i < n4; i += FT) {
        float4 v = s4[i];
        s_ssim += (double)((v.x + v.y) + (v.z + v.w));
        float4 u = m4[i];
        s_mse  += (double)((u.x + u.y) + (u.z + u.w));
    }
    const float4* p4 = (const float4*)wm_orig;
    const float4* q4 = (const float4*)wm_ext;
    int w4 = nWm >> 2;
    for (int i = tid; i < w4; i += FT) {
        float4 p = p4[i], q = q4[i];
        float a;
        a  = -(p.x*__logf(q.x) + (1.f-p.x)*__logf(1.f-q.x));
        a += -(p.y*__logf(q.y) + (1.f-p.y)*__logf(1.f-q.y));
        a += -(p.z*__logf(q.z) + (1.f-p.z)*__logf(1.f-q.z));
        a += -(p.w*__logf(q.w) + (1.f-p.w)*__logf(1.f-q.w));
        s_wl += (double)a;
    }
#pragma unroll
    for (int off = 32; off > 0; off >>= 1) {
        s_ssim += __shfl_down(s_ssim, off);
        s_mse  += __shfl_down(s_mse, off);
        s_wl   += __shfl_down(s_wl, off);
    }
    int wid = tid >> 6, lane = tid & 63;
    if (lane == 0) { red[wid] = s_ssim; red[16+wid] = s_mse; red[32+wid] = s_wl; }
    __syncthreads();
    if (tid == 0) {
        double ssim_sum = 0.0, mse_sum = 0.0, wl_sum = 0.0;
        for (int i = 0; i < 16; ++i) {
            ssim_sum += red[i]; mse_sum += red[16+i]; wl_sum += red[32+i];
        }
        float sv = (float)(ssim_sum * inv_npix);
        float ml = (float)(mse_sum  * inv_npix);
        float wl = (float)(wl_sum   * inv_nwm);
        int e = *epoch_p;
        float w_img, w_ssim;
        if (e <= 12) {
            w_img = 0.05f; w_ssim = 0.05f;
        } else {
            float progress = fminf(1.0f, (float)(e - 12) / 10.0f);
            w_img  = 0.05f + (0.5f - 0.05f)*progress;
            w_ssim = 0.05f + (0.8f - 0.05f)*progress;
        }
        float sl = 1.0f - sv;
        float total = w_img*ml + w_ssim*sl + 3.0f*wl;
        out[0] = total;
        out[1] = ml;
        out[2] = sv;
        out[3] = wl;
    }
}

extern "C" void kernel_launch(void* const* d_in, const int* in_sizes, int n_in,
                              void* d_out, int out_size, void* d_ws, size_t ws_size,
                              hipStream_t stream) {
    const float* cover   = (const float*)d_in[0];
    const float* wmed    = (const float*)d_in[1];
    const float* wm_orig = (const float*)d_in[2];
    const float* wm_ext  = (const float*)d_in[3];
    const int*   epoch   = (const int*)d_in[4];
    float* out = (float*)d_out;

    int npix   = in_sizes[0];                 // 12,582,912
    int planes = npix / (H_IMG * W_IMG);      // 48
    int nWm    = in_sizes[2];                 // 16,384

    dim3 grid(W_IMG/TW, H_IMG/TH, planes);    // 16 x 16 x 48 = 12288 blocks
    int nParts = grid.x * grid.y * grid.z;
    float* part = (float*)d_ws;               // 2 * nParts floats (98 KB)

    ssim_mse_tile<<<grid, NTHREADS, 0, stream>>>(cover, wmed, part, nParts);
    finalize_k<<<1, FT, 0, stream>>>(part, nParts, wm_orig, wm_ext, nWm,
                                     epoch, out,
                                     1.0 / (double)npix, 1.0 / (double)nWm);
}

// Round 3
// 206.549 us; speedup vs baseline: 1.3565x; 1.1238x over previous
//
#include <hip/hip_runtime.h>
#include <math.h>

// Problem constants (B=16, C=3 -> 48 planes of 512x512)
#define H_IMG 512
#define W_IMG 512
#define TH 32
#define TW 32
#define HALO 5
#define WS11 11
#define SH (TH + 2*HALO)   // 42 rows incl. halo
#define NTHREADS 256

// rbuf layout: [row 0..41][field 0..4][col 0..31], field stride 33, row 165.
// Banks: addr%32 = (5r + f + c)%32 -> stage-B lanes (c=0..31) are a
// permutation (conflict-free); stage-A writes are 2-way (free).
#define RWF 33
#define RWR (5*RWF)        // 165
#define RBUF_N (SH*RWR)    // 6930 floats = 27720 B

// Gaussian 11-tap, sigma=1.5, normalized (outer(w,w) == ref 2D window).
#define W0 0.00102838f
#define W1 0.00759873f
#define W2 0.03600075f
#define W3 0.10936070f
#define W4 0.21300556f
#define W5 0.26601172f
__device__ __constant__ float c_w[WS11] = {W0,W1,W2,W3,W4,W5,W4,W3,W2,W1,W0};

__global__ __launch_bounds__(NTHREADS) void ssim_mse_tile(
        const float* __restrict__ cover, const float* __restrict__ wmed,
        float* __restrict__ part, int nParts) {
    __shared__ __align__(16) float rbuf[RBUF_N];   // 27720 B
    __shared__ float red[8];

    const int tid = threadIdx.x;
    const size_t pbase = (size_t)blockIdx.z * (H_IMG*W_IMG);
    const float* xp = wmed + pbase;     // x = wmed, y = cover (as in reference)
    const float* yp = cover + pbase;
    const int ty0 = blockIdx.y*TH - HALO;
    const int tx0 = blockIdx.x*TW - HALO;
    const bool xin = (blockIdx.x != 0) && (blockIdx.x != gridDim.x - 1);

    // ---- Stage A: horizontal 11-tap conv of 5 fields, direct from global ----
    // 42 rows x 8 col-groups = 336 tasks; each task: 4 outputs from 14 inputs.
    float mse_acc = 0.f;
    for (int t = tid; t < SH*8; t += NTHREADS) {
        const int r = t >> 3, c0 = (t & 7) << 2;
        const int gy = ty0 + r;
        const bool rok = (unsigned)gy < (unsigned)H_IMG;
        const int gc = tx0 + c0;                    // col of j=0
        const float* prx = xp + (size_t)(rok ? gy : 0) * W_IMG + gc;
        const float* pry = yp + (size_t)(rok ? gy : 0) * W_IMG + gc;
        float xv[14], yv[14];
        if (rok && xin) {
#pragma unroll
            for (int j = 0; j < 14; ++j) { xv[j] = prx[j]; yv[j] = pry[j]; }
        } else if (rok) {
#pragma unroll
            for (int j = 0; j < 14; ++j) {
                bool ok = (unsigned)(gc + j) < (unsigned)W_IMG;
                xv[j] = ok ? prx[j] : 0.f;
                yv[j] = ok ? pry[j] : 0.f;
            }
        } else {
#pragma unroll
            for (int j = 0; j < 14; ++j) { xv[j] = 0.f; yv[j] = 0.f; }
        }

        // fused MSE: interior pixels of this tile are j=5..8, rows 5..36
        if (rok && r >= HALO && r < HALO+TH) {
#pragma unroll
            for (int j = 5; j < 9; ++j) {
                float d = xv[j] - yv[j];
                mse_acc = fmaf(d, d, mse_acc);
            }
        }

        float a0[4]={0,0,0,0}, a1[4]={0,0,0,0}, a2[4]={0,0,0,0};
        float a3[4]={0,0,0,0}, a4[4]={0,0,0,0};
#pragma unroll
        for (int j = 0; j < 14; ++j) {
            float px = xv[j], py = yv[j];
            float pxx = px*px, pyy = py*py, pxy = px*py;
#pragma unroll
            for (int k = 0; k < 4; ++k) {
                int tap = j - k;                    // compile-time resolved
                if (tap >= 0 && tap < WS11) {
                    float wv = c_w[tap];
                    a0[k] = fmaf(wv, px,  a0[k]);
                    a1[k] = fmaf(wv, py,  a1[k]);
                    a2[k] = fmaf(wv, pxx, a2[k]);
                    a3[k] = fmaf(wv, pyy, a3[k]);
                    a4[k] = fmaf(wv, pxy, a4[k]);
                }
            }
        }
        float* wb = &rbuf[r*RWR + c0];
#pragma unroll
        for (int k = 0; k < 4; ++k) {
            wb[0*RWF + k] = a0[k];
            wb[1*RWF + k] = a1[k];
            wb[2*RWF + k] = a2[k];
            wb[3*RWF + k] = a3[k];
            wb[4*RWF + k] = a4[k];
        }
    }
    __syncthreads();

    // ---- Stage B: vertical 11-tap conv + SSIM; 4 outputs/thread (column) ----
    const float C1 = 0.01f*0.01f, C2 = 0.03f*0.03f;
    const int c  = tid & 31;
    const int r0 = (tid >> 5) << 2;
    float m0[4]={0,0,0,0}, m1[4]={0,0,0,0}, e2[4]={0,0,0,0};
    float e3[4]={0,0,0,0}, e4[4]={0,0,0,0};
#pragma unroll
    for (int i = 0; i < 14; ++i) {
        const float* rb = &rbuf[(r0 + i)*RWR + c];
        float v0 = rb[0*RWF], v1 = rb[1*RWF], v2 = rb[2*RWF];
        float v3 = rb[3*RWF], v4 = rb[4*RWF];
#pragma unroll
        for (int k = 0; k < 4; ++k) {
            int tap = i - k;
            if (tap >= 0 && tap < WS11) {
                float wv = c_w[tap];
                m0[k] = fmaf(wv, v0, m0[k]);
                m1[k] = fmaf(wv, v1, m1[k]);
                e2[k] = fmaf(wv, v2, e2[k]);
                e3[k] = fmaf(wv, v3, e3[k]);
                e4[k] = fmaf(wv, v4, e4[k]);
            }
        }
    }
    float ssim_acc = 0.f;
#pragma unroll
    for (int k = 0; k < 4; ++k) {
        float mx = m0[k], my = m1[k];
        float sxx = e2[k] - mx*mx;
        float syy = e3[k] - my*my;
        float sxy = e4[k] - mx*my;
        float num = (2.f*mx*my + C1) * (2.f*sxy + C2);
        float den = (mx*mx + my*my + C1) * (sxx + syy + C2);
        ssim_acc += __fdividef(num, den);
    }

    // ---- Block reduce (4 waves of 64) ----
#pragma unroll
    for (int off = 32; off > 0; off >>= 1) {
        ssim_acc += __shfl_down(ssim_acc, off);
        mse_acc  += __shfl_down(mse_acc, off);
    }
    int wid = tid >> 6, lane = tid & 63;
    if (lane == 0) { red[wid] = ssim_acc; red[4+wid] = mse_acc; }
    __syncthreads();
    if (tid == 0) {
        float s = red[0]+red[1]+red[2]+red[3];
        float m = red[4]+red[5]+red[6]+red[7];
        int bid = (blockIdx.z*gridDim.y + blockIdx.y)*gridDim.x + blockIdx.x;
        part[bid] = s;
        part[nParts + bid] = m;
    }
}

// 1024-thread finalize: vectorized partial reduce (double), fast-log BCE,
// curriculum weights.
#define FT 1024
__global__ __launch_bounds__(FT) void finalize_k(
        const float* __restrict__ part, int nParts,
        const float* __restrict__ wm_orig, const float* __restrict__ wm_ext,
        int nWm, const int* __restrict__ epoch_p,
        float* __restrict__ out, double inv_npix, double inv_nwm) {
    __shared__ double red[48];
    int tid = threadIdx.x;
    double s_ssim = 0.0, s_mse = 0.0, s_wl = 0.0;
    const float4* s4 = (const float4*)part;
    const float4* m4 = (const float4*)(part + nParts);
    int n4 = nParts >> 2;
    for (int i = tid; i < n4; i += FT) {
        float4 v = s4[i];
        s_ssim += (double)((v.x + v.y) + (v.z + v.w));
        float4 u = m4[i];
        s_mse  += (double)((u.x + u.y) + (u.z + u.w));
    }
    const float4* p4 = (const float4*)wm_orig;
    const float4* q4 = (const float4*)wm_ext;
    int w4 = nWm >> 2;
    for (int i = tid; i < w4; i += FT) {
        float4 p = p4[i], q = q4[i];
        float a;
        a  = -(p.x*__logf(q.x) + (1.f-p.x)*__logf(1.f-q.x));
        a += -(p.y*__logf(q.y) + (1.f-p.y)*__logf(1.f-q.y));
        a += -(p.z*__logf(q.z) + (1.f-p.z)*__logf(1.f-q.z));
        a += -(p.w*__logf(q.w) + (1.f-p.w)*__logf(1.f-q.w));
        s_wl += (double)a;
    }
#pragma unroll
    for (int off = 32; off > 0; off >>= 1) {
        s_ssim += __shfl_down(s_ssim, off);
        s_mse  += __shfl_down(s_mse, off);
        s_wl   += __shfl_down(s_wl, off);
    }
    int wid = tid >> 6, lane = tid & 63;
    if (lane == 0) { red[wid] = s_ssim; red[16+wid] = s_mse; red[32+wid] = s_wl; }
    __syncthreads();
    if (tid == 0) {
        double ssim_sum = 0.0, mse_sum = 0.0, wl_sum = 0.0;
        for (int i = 0; i < 16; ++i) {
            ssim_sum += red[i]; mse_sum += red[16+i]; wl_sum += red[32+i];
        }
        float sv = (float)(ssim_sum * inv_npix);
        float ml = (float)(mse_sum  * inv_npix);
        float wl = (float)(wl_sum   * inv_nwm);
        int e = *epoch_p;
        float w_img, w_ssim;
        if (e <= 12) {
            w_img = 0.05f; w_ssim = 0.05f;
        } else {
            float progress = fminf(1.0f, (float)(e - 12) / 10.0f);
            w_img  = 0.05f + (0.5f - 0.05f)*progress;
            w_ssim = 0.05f + (0.8f - 0.05f)*progress;
        }
        float sl = 1.0f - sv;
        float total = w_img*ml + w_ssim*sl + 3.0f*wl;
        out[0] = total;
        out[1] = ml;
        out[2] = sv;
        out[3] = wl;
    }
}

extern "C" void kernel_launch(void* const* d_in, const int* in_sizes, int n_in,
                              void* d_out, int out_size, void* d_ws, size_t ws_size,
                              hipStream_t stream) {
    const float* cover   = (const float*)d_in[0];
    const float* wmed    = (const float*)d_in[1];
    const float* wm_orig = (const float*)d_in[2];
    const float* wm_ext  = (const float*)d_in[3];
    const int*   epoch   = (const int*)d_in[4];
    float* out = (float*)d_out;

    int npix   = in_sizes[0];                 // 12,582,912
    int planes = npix / (H_IMG * W_IMG);      // 48
    int nWm    = in_sizes[2];                 // 16,384

    dim3 grid(W_IMG/TW, H_IMG/TH, planes);    // 16 x 16 x 48 = 12288 blocks
    int nParts = grid.x * grid.y * grid.z;
    float* part = (float*)d_ws;               // 2 * nParts floats (98 KB)

    ssim_mse_tile<<<grid, NTHREADS, 0, stream>>>(cover, wmed, part, nParts);
    finalize_k<<<1, FT, 0, stream>>>(part, nParts, wm_orig, wm_ext, nWm,
                                     epoch, out,
                                     1.0 / (double)npix, 1.0 / (double)nWm);
}